// Round 13
// baseline (239.082 us; speedup 1.0000x reference)
//
#include <hip/hip_runtime.h>

// LearnableGlobalLocalMultiheadAttention — round 25.
// r24 post-mortem: exp2 fold bought only ~1.6 us (237.0 total) => VALU count
// no longer tightly binding; attn drifting to latency-bound. Session wobble
// in per-kernel dur; trust wall-clock.
// r25 (attn phase 2+3 ONLY; rest r24 verbatim): SINGLE-EXP SCAN via row-max
// prenormalization. exp2(x-m) <= 1 is fp16-safe => the totals pass and the
// value pass collapse into ONE exp pass; normalization commutes with the
// (linear) scan and becomes one packed multiply at scan output.
//   - packed pk_max row-max (31 in-lane + 5 butterfly)
//   - pk_sub, 64 exp2 f32, f32 totals, v_cvt_pkrtz pack (32)
//   - unnormalized fp16 packed scan (values <=1), pk_mul by (inv0,inv1) at
//     write-back; edges scaled identically.
// Removes ~64 exp + 64 cvt + 64 mul per lane; adds ~70 pk ops. Same softmax
// math (max-subtraction). Predict: total 237 -> ~230-234, absmax 0.03125.
//
// Algorithmic core (verified r1-11): triu*mini = kron(triu32,triu32)
// =>  A @ triu   == 2D inclusive prefix-sum of each row viewed as [32][32]
//     A @ triu^T == suffix sum; after softmax the 2D total == 1.0 exactly.

typedef _Float16 v8h __attribute__((ext_vector_type(8)));
typedef _Float16 v4h __attribute__((ext_vector_type(4)));
typedef _Float16 v2h __attribute__((ext_vector_type(2)));
typedef float    v4f __attribute__((ext_vector_type(4)));

#define SL 1048576   // halves per packed slice (32 bh * 1024 * 32)
#define RS 1032      // LDS row stride in fp16 elems (1024 + 8 pad)

static constexpr float SCALE = 0.17677669529663687f; // 32^-0.5
static constexpr float LOG2E = 1.4426950408889634f;

// ws layout (bytes):
//   [0, 18874368)         : 9 packed fp16 slices, slice i at i*SL halves
//       q-type {0,3,5,7} / k-type {1,4,6,8}: [bh][tile(64)][lane(64)][8]
//       slice 2 (v), PV-B: [bh][kc(32)][nt(2)][lane(64)][8]
//   [18874368, +4 MB)     : attn_pre fp32 [4096][256]
//   [23068672, +64 MB)    : pmask fp16 [32][64 rt][16384] fragment order:
//                           half index = jt*256 + q*16 + c (r18 transposed)
//   [90177536, +6 MB)     : X16 fp16 {q,k,v} [4096][256] each
//   [96468992, +1.2 MB)   : W16 fp16 [2304][256]

// ---------------- Kernel 0: fp32 -> fp16 conversion (r12) ----------------
__global__ __launch_bounds__(256)
void cvt_kernel(const float* __restrict__ q, const float* __restrict__ k,
                const float* __restrict__ v, const float* __restrict__ W,
                _Float16* __restrict__ X16, _Float16* __restrict__ W16)
{
    const int b = blockIdx.x;
    const int t = threadIdx.x;
    const float* src; _Float16* dst; int off;
    if (b < 512)       { src = q; dst = X16;             off = b; }
    else if (b < 1024) { src = k; dst = X16 + (1 << 20); off = b - 512; }
    else if (b < 1536) { src = v; dst = X16 + (2 << 20); off = b - 1024; }
    else               { src = W; dst = W16;             off = b - 1536; }
    const int i = off * 2048 + t * 8;
    const float4 a = *(const float4*)(src + i);
    const float4 c = *(const float4*)(src + i + 4);
    v8h h;
    h[0] = (_Float16)a.x; h[1] = (_Float16)a.y; h[2] = (_Float16)a.z; h[3] = (_Float16)a.w;
    h[4] = (_Float16)c.x; h[5] = (_Float16)c.y; h[6] = (_Float16)c.z; h[7] = (_Float16)c.w;
    *(v8h*)(dst + i) = h;
}

// ---------------- Kernel 1: packed input projection (r21 + r24 LOG2E fold) ----------------
__global__ __launch_bounds__(256)
void proj_kernel(const _Float16* __restrict__ X16, const _Float16* __restrict__ W16,
                 const float* __restrict__ bias, _Float16* __restrict__ P)
{
    __shared__ __align__(16) _Float16 stage[8192];   // 16 KB
    const int t   = threadIdx.x;
    const int swz = (blockIdx.x & 7) * 144 + (blockIdx.x >> 3);
    const int n0  = (swz % 18) * 128; // output column tile (0..2303)
    const int m0  = (swz / 18) * 64;  // row tile (0..4095), row = s*4 + b
    const int slice = n0 >> 8;        // uniform per block
    const int q4 = (n0 >> 7) & 1;     // 128-col half within slice
    const bool kslice = (slice == 1) || (slice == 4) || (slice == 6) || (slice == 8);
    const _Float16* X = X16 + (slice == 2 ? (2 << 20) : (kslice ? (1 << 20) : 0));
    const int w = t >> 6, lane = t & 63, m16 = lane & 15, kg = lane >> 4;
    const v4f zero = {0.f, 0.f, 0.f, 0.f};
    v4f acc[8] = {zero, zero, zero, zero, zero, zero, zero, zero};
    const _Float16* Arow = X + (size_t)(m0 + w * 16 + m16) * 256 + kg * 8;
    const _Float16* B0   = W16 + (size_t)(n0 + m16) * 256 + kg * 8;
#pragma unroll
    for (int kk = 0; kk < 8; ++kk) {
        const v8h a = *(const v8h*)(Arow + kk * 32);
#pragma unroll
        for (int nf = 0; nf < 8; ++nf) {
            const v8h bb = *(const v8h*)(B0 + nf * 4096 + kk * 32);
            acc[nf] = __builtin_amdgcn_mfma_f32_16x16x32_f16(a, bb, acc[nf], 0, 0, 0);
        }
    }
    // r24: fold log2e into the q-side of every exp'd product so attn uses
    // bare v_exp_f32 (base-2). Slices 0,7 feed phase-4's exp (also carry
    // SCALE); slices 3,5 feed phase-2's exp via the L/R logits.
    const float scale = (slice == 0 || slice == 7) ? SCALE * LOG2E
                      : (slice == 3 || slice == 5) ? LOG2E : 1.0f;
    // ---- stage into LDS with the packed-layout bijection ----
#pragma unroll
    for (int nf = 0; nf < 8; ++nf) {
        const int c = n0 + nf * 16 + m16;
        const float bv = bias[c];
#pragma unroll
        for (int i = 0; i < 4; ++i) {
            const _Float16 val = (_Float16)((acc[nf][i] + bv) * scale);
            const int lb = i * 4 + (nf >> 1);          // local bh 0..15
            int inner;
            if (slice == 2) {
                const int ls = w * 4 + kg;             // local row-quad
                inner = ((nf & 1) << 8) + ((ls >> 3) << 7) + m16 * 8 + (ls & 7);
            } else {
                inner = ((w * 4 + kg) + (((nf & 1) * 2 + (m16 >> 3)) << 4)) * 8 + (m16 & 7);
            }
            stage[lb * 512 + inner] = val;
        }
    }
    __syncthreads();
    // ---- coalesced copy-out: thread t -> 32 contiguous halves ----
    {
        const int o  = t * 32;
        const int lb = o >> 9;
        const int inner = o & 511;
        const int bs = lb >> 2, hh = lb & 3;
        const int bh = bs * 8 + q4 * 4 + hh;
        size_t dst;
        if (slice == 2) {
            const int kc = m0 >> 7;                    // s0>>5, constant per block
            const int g0 = (m0 >> 5) & 3;              // (s0>>3)&3, in {0,2}
            const int nt = inner >> 8, a2 = (inner >> 7) & 1, r = inner & 127;
            dst = (size_t)2 * SL + (size_t)bh * 32768
                + (size_t)(kc * 1024 + nt * 512 + (g0 + a2) * 128 + r);
        } else {
            const int tile = m0 >> 6;
            dst = (size_t)slice * SL + (size_t)bh * 32768 + (size_t)(tile * 512 + inner);
        }
#pragma unroll
        for (int h8 = 0; h8 < 4; ++h8)
            *(v8h*)(P + dst + h8 * 8) = *(const v8h*)(stage + o + h8 * 8);
    }
}

// ---------------- Kernel 2: fused MFMA attention (r25: single-exp scan) ----------------
// 2048 blocks x 512 threads (8 waves): xcd = bid&7, q = bid>>3;
// bh = xcd*4 + (q&3), rt = q>>2. (512,4): 16 waves/CU target. 4 barriers.
__global__ __launch_bounds__(512, 4)
void attn_kernel(const _Float16* __restrict__ P, float* __restrict__ attn_pre,
                 _Float16* __restrict__ pmask)
{
    __shared__ __align__(16) _Float16 Lh[16 * RS];
    __shared__ __align__(16) _Float16 Rh[16 * RS];
    __shared__ __align__(16) _Float16 Ledge[16][36];   // [q][jr]: 0, S(31,jr-1)
    __shared__ __align__(16) _Float16 Redge[16][36];
    __shared__ float Zp[8][16];                        // per-wave row sums

    const int t    = threadIdx.x;
    const int bid  = blockIdx.x;
    const int q    = bid >> 3;
    const int bh   = ((bid & 7) << 2) + (q & 3);
    const int rt   = q >> 2;
    const int w    = __builtin_amdgcn_readfirstlane(t >> 6);
    const int lane = t & 63;
    const int m16  = lane & 15;
    const int kg   = lane >> 4;

    const _Float16* Pb = P + (size_t)bh * 32768;
    const v4f zero = {0.f, 0.f, 0.f, 0.f};

    // ---- Phase 1: left/right logits via SWAPPED MFMA -> row-major v4h writes ----
    {
        const v8h a_l = *(const v8h*)(Pb + 3 * SL + rt * 512 + lane * 8);
        const v8h a_r = *(const v8h*)(Pb + 5 * SL + rt * 512 + lane * 8);
        const _Float16* Bl = Pb + 4 * SL;
        const _Float16* Br = Pb + 6 * SL;
#pragma unroll 4
        for (int jt2 = 0; jt2 < 8; ++jt2) {
            const int jt = (w << 3) + jt2;
            const v8h bL = *(const v8h*)(Bl + jt * 512 + lane * 8);
            const v8h bR = *(const v8h*)(Br + jt * 512 + lane * 8);
            v4f cL = __builtin_amdgcn_mfma_f32_16x16x32_f16(bL, a_l, zero, 0, 0, 0);
            v4f cR = __builtin_amdgcn_mfma_f32_16x16x32_f16(bR, a_r, zero, 0, 0, 0);
            v4h hL, hR;
#pragma unroll
            for (int i = 0; i < 4; ++i) { hL[i] = (_Float16)cL[i]; hR[i] = (_Float16)cR[i]; }
            const int base = m16 * RS + (jt << 4) + (kg << 2);
            *(v4h*)&Lh[base] = hL;
            *(v4h*)&Rh[base] = hR;
        }
    }
    __syncthreads();

    // ---- Phase 2+3 (r25): max-prenormalized single-exp packed scan ----
    // lanes<32: L rows, lanes>=32: R rows; lane kr owns cols {kb*32+kr} of
    // BOTH rows (w*2, w*2+1), packed lo/hi in one u32 per kb.
    {
        const int kr = lane & 31;
        const int row0 = w << 1;
        _Float16* R0 = (lane >= 32) ? &Rh[row0 * RS] : &Lh[row0 * RS];
        _Float16* R1 = (lane >= 32) ? &Rh[(row0 + 1) * RS] : &Lh[(row0 + 1) * RS];
        _Float16* E0 = (lane >= 32) ? &Redge[row0][0] : &Ledge[row0][0];
        _Float16* E1 = (lane >= 32) ? &Redge[row0 + 1][0] : &Ledge[row0 + 1][0];
        v2h x[32];
        // load raw logits packed (row0 in lo, row1 in hi)
#pragma unroll
        for (int kb = 0; kb < 32; ++kb) {
            v2h pr;
            pr[0] = R0[(kb << 5) + kr];
            pr[1] = R1[(kb << 5) + kr];
            x[kb] = pr;
        }
        // packed row max: in-lane tree + cross-lane butterfly
        v2h mx = x[0];
#pragma unroll
        for (int kb = 1; kb < 32; ++kb) mx = __builtin_elementwise_max(mx, x[kb]);
#pragma unroll
        for (int off = 1; off < 32; off <<= 1) {
            const int ym = __shfl_xor(__builtin_bit_cast(int, mx), off, 32);
            mx = __builtin_elementwise_max(mx, __builtin_bit_cast(v2h, ym));
        }
        // single exp pass: e = exp2(x - m) <= 1 (fp16-safe), f32 totals
        float t0 = 0.f, t1 = 0.f;
#pragma unroll
        for (int kb = 0; kb < 32; ++kb) {
            const v2h xm = x[kb] - mx;                 // v_pk_add_f16(neg)
            const float e0 = __builtin_amdgcn_exp2f((float)xm[0]);
            const float e1 = __builtin_amdgcn_exp2f((float)xm[1]);
            t0 += e0; t1 += e1;
            v2h ee; ee[0] = (_Float16)e0; ee[1] = (_Float16)e1;
            x[kb] = ee;
        }
#pragma unroll
        for (int off = 1; off < 32; off <<= 1) {
            t0 += __shfl_xor(t0, off, 32);
            t1 += __shfl_xor(t1, off, 32);
        }
        v2h invp; invp[0] = (_Float16)(1.f / t0); invp[1] = (_Float16)(1.f / t1);
        // cross-lane scan along kr of UNNORMALIZED values, both rows per shfl
#pragma unroll
        for (int kb = 0; kb < 32; ++kb) {
#pragma unroll
            for (int off = 1; off < 32; off <<= 1) {
                const int y = __shfl_up(__builtin_bit_cast(int, x[kb]), off, 32);
                if (kr >= off) x[kb] += __builtin_bit_cast(v2h, y);
            }
        }
        // in-lane cross-kb prefix
#pragma unroll
        for (int kb = 1; kb < 32; ++kb) x[kb] += x[kb - 1];
        // normalize at output (scan is linear; scaling commutes) + write back
#pragma unroll
        for (int kb = 0; kb < 32; ++kb) {
            const v2h o = x[kb] * invp;                // v_pk_mul_f16
            R0[(kb << 5) + kr] = o[0];
            R1[(kb << 5) + kr] = o[1];
            if (kb == 31) {
                E0[kr + 1] = o[0];
                E1[kr + 1] = o[1];
            }
        }
        if (kr == 0) { E0[0] = (_Float16)0.f; E1[0] = (_Float16)0.f; }
    }
    __syncthreads();

    // ---- Phase 4: logits + mask + EXP2 + row-sum; mk -> pmask; p4 carry ----
    v4h p4[8];
    float psum = 0.f;
    {
        _Float16* pm = pmask + (size_t)bh * 1048576 + (size_t)rt * 16384;
        const v8h a_g = *(const v8h*)(Pb + 0 * SL + rt * 512 + lane * 8);
        const v8h a_c = *(const v8h*)(Pb + 7 * SL + rt * 512 + lane * 8);
        const _Float16* Bg = Pb + 1 * SL;
        const _Float16* Bc = Pb + 8 * SL;
        const int rr = m16 * RS;
#pragma unroll
        for (int jt2 = 0; jt2 < 8; ++jt2) {
            const int jt   = (w << 3) + jt2;
            const int jb   = jt >> 1;
            const int jr0  = ((jt & 1) << 4) + (kg << 2);
            const int colb = (jt << 4) + (kg << 2);
            const v8h bG = *(const v8h*)(Bg + jt * 512 + lane * 8);
            const v8h bC = *(const v8h*)(Bc + jt * 512 + lane * 8);
            const v4f g4 = __builtin_amdgcn_mfma_f32_16x16x32_f16(bG, a_g, zero, 0, 0, 0);
            const v4f l4 = __builtin_amdgcn_mfma_f32_16x16x32_f16(bC, a_c, zero, 0, 0, 0);
            const v4h PLv  = *(const v4h*)&Lh[rr + colb];
            const v4h PRv  = *(const v4h*)&Rh[rr + colb];
            const v4h eLcv = *(const v4h*)&Ledge[m16][jr0];
            const v4h eRcv = *(const v4h*)&Redge[m16][jr0];
            float eLb = 0.f, eRb = 0.f;
            if (jb) {
                eLb = (float)Lh[rr + (jb << 5) - 1];
                eRb = (float)Rh[rr + (jb << 5) - 1];
            }
            v4h m4;
#pragma unroll
            for (int i = 0; i < 4; ++i) {
                const int jrv = jr0 + i;
                const float PL  = (float)PLv[i];
                const float PR  = (float)PRv[i];
                const float eLc = (float)eLcv[i];
                const float eRc = (float)eRcv[i];
                float eLbc = 0.f, eRbc = 0.f;
                if (jb && jrv) {
                    const int o = rr + ((jb - 1) << 5) + jrv - 1;
                    eLbc = (float)Lh[o];
                    eRbc = (float)Rh[o];
                }
                const float SLv = 1.0f - eLb - eLc + eLbc;
                const float SRv = 1.0f - eRb - eRc + eRbc;
                const float mkv = PL * SRv + SLv * PR;
                const float pv  = __builtin_amdgcn_exp2f(0.1f * g4[i] + l4[i] * mkv);
                p4[jt2][i] = (_Float16)pv;
                psum += pv;
                m4[i] = (_Float16)mkv;
            }
            *(v4h*)(pm + ((size_t)jt << 8) + (m16 << 4) + (kg << 2)) = m4;
        }
        // reduce partial sum over the 4 kg-lanes sharing row m16
        psum += __shfl_xor(psum, 16);
        psum += __shfl_xor(psum, 32);
        if (lane < 16) Zp[w][m16] = psum;
    }
    __syncthreads();   // scan reads done + Zp published

    // ---- Phase 4b': cross-wave denominator + normalized S~ write ----
    {
        float Z = 0.f;
#pragma unroll
        for (int w8 = 0; w8 < 8; ++w8) Z += Zp[w8][m16];
        const float inv = 1.f / Z;
#pragma unroll
        for (int jt2 = 0; jt2 < 8; ++jt2) {
            v4h o;
#pragma unroll
            for (int i = 0; i < 4; ++i) o[i] = (_Float16)((float)p4[jt2][i] * inv);
            *(v4h*)&Lh[m16 * RS + (((w << 3) + jt2) << 4) + (kg << 2)] = o;
        }
    }
    __syncthreads();

    // ---- Phase 6: PV via MFMA. wave = (nt = d-half, hf = j-quarter) ----
    {
        const int nt = w & 1, hf = w >> 1;
        v4f c = zero;
        const _Float16* Vb = Pb + 2 * SL + nt * 512 + lane * 8;
        const int kc0 = hf << 3;
#pragma unroll 4
        for (int kc2 = 0; kc2 < 8; ++kc2) {
            const int kc = kc0 + kc2;
            const v8h a = *(const v8h*)&Lh[m16 * RS + (kc << 5) + (kg << 3)];
            const v8h b = *(const v8h*)(Vb + (size_t)kc * 1024);
            c = __builtin_amdgcn_mfma_f32_16x16x32_f16(a, b, c, 0, 0, 0);
        }
        float* Pbuf = (float*)&Rh[0];   // Rh dead since phase-4 barrier
#pragma unroll
        for (int i = 0; i < 4; ++i) Pbuf[(w << 8) + (lane << 2) + i] = c[i];
    }
    __syncthreads();

    // ---- Epilogue: fold 4 j-quarters, coalesced d-fastest store ----
    {
        const float* Pbuf = (const float*)&Rh[0];
        const int r   = t >> 5;                    // row in tile (0..15)
        const int d   = t & 31;
        const int nt2 = d >> 4, n = d & 15;
        const int kg2 = r >> 2, i2 = r & 3;
        const int off = (kg2 << 6) + (n << 2) + i2;   // lane*4 + i
        float v = 0.f;
#pragma unroll
        for (int hf = 0; hf < 4; ++hf)
            v += Pbuf[(((hf << 1) + nt2) << 8) + off];
        const int srow = (rt << 4) + r;
        attn_pre[((size_t)(srow * 4 + (bh >> 3))) * 256 + (bh & 7) * 32 + d] = v;
    }
}

// ---------------- Kernel 3: fused tail — outproj (blocks 0..255) + cmask (256..767) ----
__global__ __launch_bounds__(256)
void tail_kernel(const _Float16* __restrict__ pmask, float* __restrict__ cmask,
                 const float* __restrict__ A, const float* __restrict__ W,
                 const float* __restrict__ bias, float* __restrict__ C)
{
    __shared__ __align__(16) float SMEM[4 * 16 * 136];   // 34816 B
    const int bid = blockIdx.x;
    const int t = threadIdx.x;

    if (bid >= 256) {
        // ---- cmask part: 512 blocks, grid-equivalent (64 rt, 8 wh) ----
        const int b2 = bid - 256;
        const int rt = b2 >> 3, wh = b2 & 7;
        float (*T4)[16][136] = (float(*)[16][136])SMEM;
        const int wv = t >> 6;                            // wave -> bh octet
        const int lane = t & 63;
        float acc[8][4] = {};
        const _Float16* base = pmask + (size_t)rt * 16384 + ((size_t)wh << 11) + (lane << 2)
                             + ((size_t)wv << 3) * 1048576;
        for (int bh = 0; bh < 8; ++bh) {
            const _Float16* p = base + (size_t)bh * 1048576;
#pragma unroll
            for (int jt2 = 0; jt2 < 8; ++jt2) {
                const v4h h4 = *(const v4h*)(p + (jt2 << 8));
#pragma unroll
                for (int i = 0; i < 4; ++i) acc[jt2][i] += (float)h4[i];
            }
        }
        // half index e = lane*4+i = q*16 + c  ->  q = lane>>2, c = (lane&3)*4+i
#pragma unroll
        for (int jt2 = 0; jt2 < 8; ++jt2)
#pragma unroll
            for (int i = 0; i < 4; ++i)
                T4[wv][lane >> 2][(jt2 << 4) + ((lane & 3) << 2) + i] = acc[jt2][i];
        __syncthreads();
        // 16 rows x 128 cols; thread t -> row t>>4, 8 consecutive cols.
        const int row = t >> 4;
        const int c0  = (t & 15) << 3;
#pragma unroll
        for (int h = 0; h < 2; ++h) {
            const int c = c0 + (h << 2);
            const float4 s0 = *(const float4*)&T4[0][row][c];
            const float4 s1 = *(const float4*)&T4[1][row][c];
            const float4 s2 = *(const float4*)&T4[2][row][c];
            const float4 s3 = *(const float4*)&T4[3][row][c];
            const float4 o = make_float4(s0.x + s1.x + s2.x + s3.x,
                                         s0.y + s1.y + s2.y + s3.y,
                                         s0.z + s1.z + s2.z + s3.z,
                                         s0.w + s1.w + s2.w + s3.w);
            *(float4*)&cmask[((size_t)((rt << 4) + row) << 10) + (wh << 7) + c] = o;
        }
    } else {
        // ---- outproj part: 256 blocks, grid-equivalent (4 n0, 64 m0) ----
        const int n0 = (bid & 3) * 64;
        const int m0 = (bid >> 2) * 64;
        float (*As)[68] = (float(*)[68])SMEM;
        float (*Bs)[68] = (float(*)[68])(SMEM + 16 * 68);
        const int tx = t & 15, ty = t >> 4;
        const int lm = t >> 2, lk = (t & 3) << 2;
        float acc[4][4] = {};
        for (int k0 = 0; k0 < 256; k0 += 16) {
            float4 av = *(const float4*)(A + (size_t)(m0 + lm) * 256 + k0 + lk);
            float4 bv = *(const float4*)(W + (size_t)(n0 + lm) * 256 + k0 + lk);
            As[lk + 0][lm] = av.x; As[lk + 1][lm] = av.y; As[lk + 2][lm] = av.z; As[lk + 3][lm] = av.w;
            Bs[lk + 0][lm] = bv.x; Bs[lk + 1][lm] = bv.y; Bs[lk + 2][lm] = bv.z; Bs[lk + 3][lm] = bv.w;
            __syncthreads();
#pragma unroll
            for (int kk = 0; kk < 16; ++kk) {
                float4 a4 = *(const float4*)&As[kk][ty << 2];
                float4 b4 = *(const float4*)&Bs[kk][tx << 2];
                float aa[4] = {a4.x, a4.y, a4.z, a4.w};
                float bb[4] = {b4.x, b4.y, b4.z, b4.w};
#pragma unroll
                for (int i = 0; i < 4; ++i)
#pragma unroll
                    for (int j = 0; j < 4; ++j)
                        acc[i][j] = fmaf(aa[i], bb[j], acc[i][j]);
            }
            __syncthreads();
        }
#pragma unroll
        for (int i = 0; i < 4; ++i) {
            const int m  = m0 + (ty << 2) + i;
            const int c0 = n0 + (tx << 2);
            float4 o = make_float4(acc[i][0] + bias[c0 + 0], acc[i][1] + bias[c0 + 1],
                                   acc[i][2] + bias[c0 + 2], acc[i][3] + bias[c0 + 3]);
            *(float4*)&C[(size_t)m * 256 + c0] = o;
        }
    }
}

extern "C" void kernel_launch(void* const* d_in, const int* in_sizes, int n_in,
                              void* d_out, int out_size, void* d_ws, size_t ws_size,
                              hipStream_t stream)
{
    const float* q  = (const float*)d_in[0];
    const float* k  = (const float*)d_in[1];
    const float* v  = (const float*)d_in[2];
    const float* Wi = (const float*)d_in[3];
    const float* bi = (const float*)d_in[4];
    const float* Wo = (const float*)d_in[5];
    const float* bo = (const float*)d_in[6];

    float* out      = (float*)d_out;
    float* attn_out = out;                 // [1024,4,256]
    float* cmask    = out + 1048576;       // [1024,1024]

    _Float16* Ppack    = (_Float16*)d_ws;
    float*    attn_pre = (float*)((char*)d_ws + 18874368);
    _Float16* pmask    = (_Float16*)((char*)d_ws + 23068672);
    _Float16* X16      = (_Float16*)((char*)d_ws + 90177536);
    _Float16* W16      = (_Float16*)((char*)d_ws + 96468992);

    cvt_kernel<<<1824, 256, 0, stream>>>(q, k, v, Wi, X16, W16);
    proj_kernel<<<1152, 256, 0, stream>>>(X16, W16, bi, Ppack);
    attn_kernel<<<2048, 512, 0, stream>>>(Ppack, attn_pre, pmask);
    tail_kernel<<<768, 256, 0, stream>>>(pmask, cmask, attn_pre, Wo, bo, attn_out);
}

// Round 14
// 236.043 us; speedup vs baseline: 1.0129x; 1.0129x over previous
//
#include <hip/hip_runtime.h>

// LearnableGlobalLocalMultiheadAttention — round 26.
// r25 post-mortem: single-exp scan NULL/regression (239.1 vs 237.0);
// VALUBusy 46->39% with dur flat => attn is latency-bound, not VALU-bound.
// Occupancy structurally capped (Lh+Rh=64KB => 2 blocks/CU).
// r26: (1) scan reverted to r24's measured-best two-pass packed form;
// (2) DEFERRED NORMALIZATION: division by row-constant Z commutes with PV
//     => phase 4b' writes RAW p4 (8 v4h stores only; deletes 32 cvt/mul and
//     the Zp-read dependency between barriers); epilogue sums Zp[8][r] and
//     divides once. Identical fp16 values stored; PV accumulates f32.
// Predict: 239.1 -> ~233-236; absmax 0.03125. If >=237: structure plateau.
//
// Algorithmic core (verified r1-11): triu*mini = kron(triu32,triu32)
// =>  A @ triu   == 2D inclusive prefix-sum of each row viewed as [32][32]
//     A @ triu^T == suffix sum; after softmax the 2D total == 1.0 exactly.

typedef _Float16 v8h __attribute__((ext_vector_type(8)));
typedef _Float16 v4h __attribute__((ext_vector_type(4)));
typedef _Float16 v2h __attribute__((ext_vector_type(2)));
typedef float    v4f __attribute__((ext_vector_type(4)));

#define SL 1048576   // halves per packed slice (32 bh * 1024 * 32)
#define RS 1032      // LDS row stride in fp16 elems (1024 + 8 pad)

static constexpr float SCALE = 0.17677669529663687f; // 32^-0.5
static constexpr float LOG2E = 1.4426950408889634f;

// ws layout (bytes):
//   [0, 18874368)         : 9 packed fp16 slices, slice i at i*SL halves
//       q-type {0,3,5,7} / k-type {1,4,6,8}: [bh][tile(64)][lane(64)][8]
//       slice 2 (v), PV-B: [bh][kc(32)][nt(2)][lane(64)][8]
//   [18874368, +4 MB)     : attn_pre fp32 [4096][256]
//   [23068672, +64 MB)    : pmask fp16 [32][64 rt][16384] fragment order:
//                           half index = jt*256 + q*16 + c (r18 transposed)
//   [90177536, +6 MB)     : X16 fp16 {q,k,v} [4096][256] each
//   [96468992, +1.2 MB)   : W16 fp16 [2304][256]

// ---------------- Kernel 0: fp32 -> fp16 conversion (r12) ----------------
__global__ __launch_bounds__(256)
void cvt_kernel(const float* __restrict__ q, const float* __restrict__ k,
                const float* __restrict__ v, const float* __restrict__ W,
                _Float16* __restrict__ X16, _Float16* __restrict__ W16)
{
    const int b = blockIdx.x;
    const int t = threadIdx.x;
    const float* src; _Float16* dst; int off;
    if (b < 512)       { src = q; dst = X16;             off = b; }
    else if (b < 1024) { src = k; dst = X16 + (1 << 20); off = b - 512; }
    else if (b < 1536) { src = v; dst = X16 + (2 << 20); off = b - 1024; }
    else               { src = W; dst = W16;             off = b - 1536; }
    const int i = off * 2048 + t * 8;
    const float4 a = *(const float4*)(src + i);
    const float4 c = *(const float4*)(src + i + 4);
    v8h h;
    h[0] = (_Float16)a.x; h[1] = (_Float16)a.y; h[2] = (_Float16)a.z; h[3] = (_Float16)a.w;
    h[4] = (_Float16)c.x; h[5] = (_Float16)c.y; h[6] = (_Float16)c.z; h[7] = (_Float16)c.w;
    *(v8h*)(dst + i) = h;
}

// ---------------- Kernel 1: packed input projection (r21 + r24 LOG2E fold) ----------------
__global__ __launch_bounds__(256)
void proj_kernel(const _Float16* __restrict__ X16, const _Float16* __restrict__ W16,
                 const float* __restrict__ bias, _Float16* __restrict__ P)
{
    __shared__ __align__(16) _Float16 stage[8192];   // 16 KB
    const int t   = threadIdx.x;
    const int swz = (blockIdx.x & 7) * 144 + (blockIdx.x >> 3);
    const int n0  = (swz % 18) * 128; // output column tile (0..2303)
    const int m0  = (swz / 18) * 64;  // row tile (0..4095), row = s*4 + b
    const int slice = n0 >> 8;        // uniform per block
    const int q4 = (n0 >> 7) & 1;     // 128-col half within slice
    const bool kslice = (slice == 1) || (slice == 4) || (slice == 6) || (slice == 8);
    const _Float16* X = X16 + (slice == 2 ? (2 << 20) : (kslice ? (1 << 20) : 0));
    const int w = t >> 6, lane = t & 63, m16 = lane & 15, kg = lane >> 4;
    const v4f zero = {0.f, 0.f, 0.f, 0.f};
    v4f acc[8] = {zero, zero, zero, zero, zero, zero, zero, zero};
    const _Float16* Arow = X + (size_t)(m0 + w * 16 + m16) * 256 + kg * 8;
    const _Float16* B0   = W16 + (size_t)(n0 + m16) * 256 + kg * 8;
#pragma unroll
    for (int kk = 0; kk < 8; ++kk) {
        const v8h a = *(const v8h*)(Arow + kk * 32);
#pragma unroll
        for (int nf = 0; nf < 8; ++nf) {
            const v8h bb = *(const v8h*)(B0 + nf * 4096 + kk * 32);
            acc[nf] = __builtin_amdgcn_mfma_f32_16x16x32_f16(a, bb, acc[nf], 0, 0, 0);
        }
    }
    // r24: fold log2e into the q-side of every exp'd product so attn uses
    // bare v_exp_f32 (base-2). Slices 0,7 feed phase-4's exp (also carry
    // SCALE); slices 3,5 feed phase-2's exp via the L/R logits.
    const float scale = (slice == 0 || slice == 7) ? SCALE * LOG2E
                      : (slice == 3 || slice == 5) ? LOG2E : 1.0f;
    // ---- stage into LDS with the packed-layout bijection ----
#pragma unroll
    for (int nf = 0; nf < 8; ++nf) {
        const int c = n0 + nf * 16 + m16;
        const float bv = bias[c];
#pragma unroll
        for (int i = 0; i < 4; ++i) {
            const _Float16 val = (_Float16)((acc[nf][i] + bv) * scale);
            const int lb = i * 4 + (nf >> 1);          // local bh 0..15
            int inner;
            if (slice == 2) {
                const int ls = w * 4 + kg;             // local row-quad
                inner = ((nf & 1) << 8) + ((ls >> 3) << 7) + m16 * 8 + (ls & 7);
            } else {
                inner = ((w * 4 + kg) + (((nf & 1) * 2 + (m16 >> 3)) << 4)) * 8 + (m16 & 7);
            }
            stage[lb * 512 + inner] = val;
        }
    }
    __syncthreads();
    // ---- coalesced copy-out: thread t -> 32 contiguous halves ----
    {
        const int o  = t * 32;
        const int lb = o >> 9;
        const int inner = o & 511;
        const int bs = lb >> 2, hh = lb & 3;
        const int bh = bs * 8 + q4 * 4 + hh;
        size_t dst;
        if (slice == 2) {
            const int kc = m0 >> 7;                    // s0>>5, constant per block
            const int g0 = (m0 >> 5) & 3;              // (s0>>3)&3, in {0,2}
            const int nt = inner >> 8, a2 = (inner >> 7) & 1, r = inner & 127;
            dst = (size_t)2 * SL + (size_t)bh * 32768
                + (size_t)(kc * 1024 + nt * 512 + (g0 + a2) * 128 + r);
        } else {
            const int tile = m0 >> 6;
            dst = (size_t)slice * SL + (size_t)bh * 32768 + (size_t)(tile * 512 + inner);
        }
#pragma unroll
        for (int h8 = 0; h8 < 4; ++h8)
            *(v8h*)(P + dst + h8 * 8) = *(const v8h*)(stage + o + h8 * 8);
    }
}

// ---------------- Kernel 2: fused MFMA attention (r26: r24 scan + deferred norm) ----------------
// 2048 blocks x 512 threads (8 waves): xcd = bid&7, q = bid>>3;
// bh = xcd*4 + (q&3), rt = q>>2. (512,4): 16 waves/CU target. 4 barriers.
__global__ __launch_bounds__(512, 4)
void attn_kernel(const _Float16* __restrict__ P, float* __restrict__ attn_pre,
                 _Float16* __restrict__ pmask)
{
    __shared__ __align__(16) _Float16 Lh[16 * RS];
    __shared__ __align__(16) _Float16 Rh[16 * RS];
    __shared__ __align__(16) _Float16 Ledge[16][36];   // [q][jr]: 0, S(31,jr-1)
    __shared__ __align__(16) _Float16 Redge[16][36];
    __shared__ float Zp[8][16];                        // per-wave row sums

    const int t    = threadIdx.x;
    const int bid  = blockIdx.x;
    const int q    = bid >> 3;
    const int bh   = ((bid & 7) << 2) + (q & 3);
    const int rt   = q >> 2;
    const int w    = __builtin_amdgcn_readfirstlane(t >> 6);
    const int lane = t & 63;
    const int m16  = lane & 15;
    const int kg   = lane >> 4;

    const _Float16* Pb = P + (size_t)bh * 32768;
    const v4f zero = {0.f, 0.f, 0.f, 0.f};

    // ---- Phase 1: left/right logits via SWAPPED MFMA -> row-major v4h writes ----
    {
        const v8h a_l = *(const v8h*)(Pb + 3 * SL + rt * 512 + lane * 8);
        const v8h a_r = *(const v8h*)(Pb + 5 * SL + rt * 512 + lane * 8);
        const _Float16* Bl = Pb + 4 * SL;
        const _Float16* Br = Pb + 6 * SL;
#pragma unroll 4
        for (int jt2 = 0; jt2 < 8; ++jt2) {
            const int jt = (w << 3) + jt2;
            const v8h bL = *(const v8h*)(Bl + jt * 512 + lane * 8);
            const v8h bR = *(const v8h*)(Br + jt * 512 + lane * 8);
            v4f cL = __builtin_amdgcn_mfma_f32_16x16x32_f16(bL, a_l, zero, 0, 0, 0);
            v4f cR = __builtin_amdgcn_mfma_f32_16x16x32_f16(bR, a_r, zero, 0, 0, 0);
            v4h hL, hR;
#pragma unroll
            for (int i = 0; i < 4; ++i) { hL[i] = (_Float16)cL[i]; hR[i] = (_Float16)cR[i]; }
            const int base = m16 * RS + (jt << 4) + (kg << 2);
            *(v4h*)&Lh[base] = hL;
            *(v4h*)&Rh[base] = hR;
        }
    }
    __syncthreads();

    // ---- Phase 2+3 (r24 form): pre-normalized packed-fp16 dual-row scan ----
    // lanes<32: L rows, lanes>=32: R rows; lane kr owns cols {kb*32+kr} of
    // BOTH rows (w*2, w*2+1), packed lo/hi in one u32 per kb.
    {
        const int kr = lane & 31;
        const int row0 = w << 1;
        _Float16* R0 = (lane >= 32) ? &Rh[row0 * RS] : &Lh[row0 * RS];
        _Float16* R1 = (lane >= 32) ? &Rh[(row0 + 1) * RS] : &Lh[(row0 + 1) * RS];
        _Float16* E0 = (lane >= 32) ? &Redge[row0][0] : &Ledge[row0][0];
        _Float16* E1 = (lane >= 32) ? &Redge[row0 + 1][0] : &Ledge[row0 + 1][0];
        v2h x[32];
        float t0 = 0.f, t1 = 0.f;
#pragma unroll
        for (int kb = 0; kb < 32; ++kb) {
            v2h pr;
            pr[0] = R0[(kb << 5) + kr];
            pr[1] = R1[(kb << 5) + kr];
            x[kb] = pr;
            t0 += __builtin_amdgcn_exp2f((float)pr[0]);
            t1 += __builtin_amdgcn_exp2f((float)pr[1]);
        }
#pragma unroll
        for (int off = 1; off < 32; off <<= 1) {
            t0 += __shfl_xor(t0, off, 32);
            t1 += __shfl_xor(t1, off, 32);
        }
        const float inv0 = 1.f / t0, inv1 = 1.f / t1;
        // in-place repack: normalized fp16 pair (values <= 1, fp16-safe)
#pragma unroll
        for (int kb = 0; kb < 32; ++kb) {
            v2h pr = x[kb];
            v2h nn;
            nn[0] = (_Float16)(__builtin_amdgcn_exp2f((float)pr[0]) * inv0);
            nn[1] = (_Float16)(__builtin_amdgcn_exp2f((float)pr[1]) * inv1);
            x[kb] = nn;
        }
        // cross-lane scan along kr, both rows per shfl (v_pk_add_f16)
#pragma unroll
        for (int kb = 0; kb < 32; ++kb) {
#pragma unroll
            for (int off = 1; off < 32; off <<= 1) {
                const int y = __shfl_up(__builtin_bit_cast(int, x[kb]), off, 32);
                if (kr >= off) x[kb] += __builtin_bit_cast(v2h, y);
            }
        }
        // in-lane cross-kb prefix
#pragma unroll
        for (int kb = 1; kb < 32; ++kb) x[kb] += x[kb - 1];
        // write back + 1-shifted edge rows (x[31] = P(31, kr))
#pragma unroll
        for (int kb = 0; kb < 32; ++kb) {
            R0[(kb << 5) + kr] = x[kb][0];
            R1[(kb << 5) + kr] = x[kb][1];
        }
        E0[kr + 1] = x[31][0];
        E1[kr + 1] = x[31][1];
        if (kr == 0) { E0[0] = (_Float16)0.f; E1[0] = (_Float16)0.f; }
    }
    __syncthreads();

    // ---- Phase 4: logits + mask + EXP2 + row-sum; mk -> pmask; p4 carry ----
    v4h p4[8];
    float psum = 0.f;
    {
        _Float16* pm = pmask + (size_t)bh * 1048576 + (size_t)rt * 16384;
        const v8h a_g = *(const v8h*)(Pb + 0 * SL + rt * 512 + lane * 8);
        const v8h a_c = *(const v8h*)(Pb + 7 * SL + rt * 512 + lane * 8);
        const _Float16* Bg = Pb + 1 * SL;
        const _Float16* Bc = Pb + 8 * SL;
        const int rr = m16 * RS;
#pragma unroll
        for (int jt2 = 0; jt2 < 8; ++jt2) {
            const int jt   = (w << 3) + jt2;
            const int jb   = jt >> 1;
            const int jr0  = ((jt & 1) << 4) + (kg << 2);
            const int colb = (jt << 4) + (kg << 2);
            const v8h bG = *(const v8h*)(Bg + jt * 512 + lane * 8);
            const v8h bC = *(const v8h*)(Bc + jt * 512 + lane * 8);
            const v4f g4 = __builtin_amdgcn_mfma_f32_16x16x32_f16(bG, a_g, zero, 0, 0, 0);
            const v4f l4 = __builtin_amdgcn_mfma_f32_16x16x32_f16(bC, a_c, zero, 0, 0, 0);
            const v4h PLv  = *(const v4h*)&Lh[rr + colb];
            const v4h PRv  = *(const v4h*)&Rh[rr + colb];
            const v4h eLcv = *(const v4h*)&Ledge[m16][jr0];
            const v4h eRcv = *(const v4h*)&Redge[m16][jr0];
            float eLb = 0.f, eRb = 0.f;
            if (jb) {
                eLb = (float)Lh[rr + (jb << 5) - 1];
                eRb = (float)Rh[rr + (jb << 5) - 1];
            }
            v4h m4;
#pragma unroll
            for (int i = 0; i < 4; ++i) {
                const int jrv = jr0 + i;
                const float PL  = (float)PLv[i];
                const float PR  = (float)PRv[i];
                const float eLc = (float)eLcv[i];
                const float eRc = (float)eRcv[i];
                float eLbc = 0.f, eRbc = 0.f;
                if (jb && jrv) {
                    const int o = rr + ((jb - 1) << 5) + jrv - 1;
                    eLbc = (float)Lh[o];
                    eRbc = (float)Rh[o];
                }
                const float SLv = 1.0f - eLb - eLc + eLbc;
                const float SRv = 1.0f - eRb - eRc + eRbc;
                const float mkv = PL * SRv + SLv * PR;
                const float pv  = __builtin_amdgcn_exp2f(0.1f * g4[i] + l4[i] * mkv);
                p4[jt2][i] = (_Float16)pv;
                psum += pv;
                m4[i] = (_Float16)mkv;
            }
            *(v4h*)(pm + ((size_t)jt << 8) + (m16 << 4) + (kg << 2)) = m4;
        }
        // reduce partial sum over the 4 kg-lanes sharing row m16
        psum += __shfl_xor(psum, 16);
        psum += __shfl_xor(psum, 32);
        if (lane < 16) Zp[w][m16] = psum;
    }
    __syncthreads();   // scan reads done + Zp published

    // ---- Phase 4b' (r26): write RAW p4 -> Lh (deferred normalization) ----
    {
#pragma unroll
        for (int jt2 = 0; jt2 < 8; ++jt2)
            *(v4h*)&Lh[m16 * RS + (((w << 3) + jt2) << 4) + (kg << 2)] = p4[jt2];
    }
    __syncthreads();

    // ---- Phase 6: PV via MFMA on UNNORMALIZED S. wave = (nt, hf) ----
    {
        const int nt = w & 1, hf = w >> 1;
        v4f c = zero;
        const _Float16* Vb = Pb + 2 * SL + nt * 512 + lane * 8;
        const int kc0 = hf << 3;
#pragma unroll 4
        for (int kc2 = 0; kc2 < 8; ++kc2) {
            const int kc = kc0 + kc2;
            const v8h a = *(const v8h*)&Lh[m16 * RS + (kc << 5) + (kg << 3)];
            const v8h b = *(const v8h*)(Vb + (size_t)kc * 1024);
            c = __builtin_amdgcn_mfma_f32_16x16x32_f16(a, b, c, 0, 0, 0);
        }
        float* Pbuf = (float*)&Rh[0];   // Rh dead since phase-4 barrier
#pragma unroll
        for (int i = 0; i < 4; ++i) Pbuf[(w << 8) + (lane << 2) + i] = c[i];
    }
    __syncthreads();

    // ---- Epilogue: fold 4 j-quarters, divide by Z once, coalesced store ----
    {
        const float* Pbuf = (const float*)&Rh[0];
        const int r   = t >> 5;                    // row in tile (0..15)
        const int d   = t & 31;
        const int nt2 = d >> 4, n = d & 15;
        const int kg2 = r >> 2, i2 = r & 3;
        const int off = (kg2 << 6) + (n << 2) + i2;   // lane*4 + i
        float Z = 0.f;
#pragma unroll
        for (int w8 = 0; w8 < 8; ++w8) Z += Zp[w8][r];
        float v = 0.f;
#pragma unroll
        for (int hf = 0; hf < 4; ++hf)
            v += Pbuf[(((hf << 1) + nt2) << 8) + off];
        const int srow = (rt << 4) + r;
        attn_pre[((size_t)(srow * 4 + (bh >> 3))) * 256 + (bh & 7) * 32 + d] = v / Z;
    }
}

// ---------------- Kernel 3: fused tail — outproj (blocks 0..255) + cmask (256..767) ----
__global__ __launch_bounds__(256)
void tail_kernel(const _Float16* __restrict__ pmask, float* __restrict__ cmask,
                 const float* __restrict__ A, const float* __restrict__ W,
                 const float* __restrict__ bias, float* __restrict__ C)
{
    __shared__ __align__(16) float SMEM[4 * 16 * 136];   // 34816 B
    const int bid = blockIdx.x;
    const int t = threadIdx.x;

    if (bid >= 256) {
        // ---- cmask part: 512 blocks, grid-equivalent (64 rt, 8 wh) ----
        const int b2 = bid - 256;
        const int rt = b2 >> 3, wh = b2 & 7;
        float (*T4)[16][136] = (float(*)[16][136])SMEM;
        const int wv = t >> 6;                            // wave -> bh octet
        const int lane = t & 63;
        float acc[8][4] = {};
        const _Float16* base = pmask + (size_t)rt * 16384 + ((size_t)wh << 11) + (lane << 2)
                             + ((size_t)wv << 3) * 1048576;
        for (int bh = 0; bh < 8; ++bh) {
            const _Float16* p = base + (size_t)bh * 1048576;
#pragma unroll
            for (int jt2 = 0; jt2 < 8; ++jt2) {
                const v4h h4 = *(const v4h*)(p + (jt2 << 8));
#pragma unroll
                for (int i = 0; i < 4; ++i) acc[jt2][i] += (float)h4[i];
            }
        }
        // half index e = lane*4+i = q*16 + c  ->  q = lane>>2, c = (lane&3)*4+i
#pragma unroll
        for (int jt2 = 0; jt2 < 8; ++jt2)
#pragma unroll
            for (int i = 0; i < 4; ++i)
                T4[wv][lane >> 2][(jt2 << 4) + ((lane & 3) << 2) + i] = acc[jt2][i];
        __syncthreads();
        // 16 rows x 128 cols; thread t -> row t>>4, 8 consecutive cols.
        const int row = t >> 4;
        const int c0  = (t & 15) << 3;
#pragma unroll
        for (int h = 0; h < 2; ++h) {
            const int c = c0 + (h << 2);
            const float4 s0 = *(const float4*)&T4[0][row][c];
            const float4 s1 = *(const float4*)&T4[1][row][c];
            const float4 s2 = *(const float4*)&T4[2][row][c];
            const float4 s3 = *(const float4*)&T4[3][row][c];
            const float4 o = make_float4(s0.x + s1.x + s2.x + s3.x,
                                         s0.y + s1.y + s2.y + s3.y,
                                         s0.z + s1.z + s2.z + s3.z,
                                         s0.w + s1.w + s2.w + s3.w);
            *(float4*)&cmask[((size_t)((rt << 4) + row) << 10) + (wh << 7) + c] = o;
        }
    } else {
        // ---- outproj part: 256 blocks, grid-equivalent (4 n0, 64 m0) ----
        const int n0 = (bid & 3) * 64;
        const int m0 = (bid >> 2) * 64;
        float (*As)[68] = (float(*)[68])SMEM;
        float (*Bs)[68] = (float(*)[68])(SMEM + 16 * 68);
        const int tx = t & 15, ty = t >> 4;
        const int lm = t >> 2, lk = (t & 3) << 2;
        float acc[4][4] = {};
        for (int k0 = 0; k0 < 256; k0 += 16) {
            float4 av = *(const float4*)(A + (size_t)(m0 + lm) * 256 + k0 + lk);
            float4 bv = *(const float4*)(W + (size_t)(n0 + lm) * 256 + k0 + lk);
            As[lk + 0][lm] = av.x; As[lk + 1][lm] = av.y; As[lk + 2][lm] = av.z; As[lk + 3][lm] = av.w;
            Bs[lk + 0][lm] = bv.x; Bs[lk + 1][lm] = bv.y; Bs[lk + 2][lm] = bv.z; Bs[lk + 3][lm] = bv.w;
            __syncthreads();
#pragma unroll
            for (int kk = 0; kk < 16; ++kk) {
                float4 a4 = *(const float4*)&As[kk][ty << 2];
                float4 b4 = *(const float4*)&Bs[kk][tx << 2];
                float aa[4] = {a4.x, a4.y, a4.z, a4.w};
                float bb[4] = {b4.x, b4.y, b4.z, b4.w};
#pragma unroll
                for (int i = 0; i < 4; ++i)
#pragma unroll
                    for (int j = 0; j < 4; ++j)
                        acc[i][j] = fmaf(aa[i], bb[j], acc[i][j]);
            }
            __syncthreads();
        }
#pragma unroll
        for (int i = 0; i < 4; ++i) {
            const int m  = m0 + (ty << 2) + i;
            const int c0 = n0 + (tx << 2);
            float4 o = make_float4(acc[i][0] + bias[c0 + 0], acc[i][1] + bias[c0 + 1],
                                   acc[i][2] + bias[c0 + 2], acc[i][3] + bias[c0 + 3]);
            *(float4*)&C[(size_t)m * 256 + c0] = o;
        }
    }
}

extern "C" void kernel_launch(void* const* d_in, const int* in_sizes, int n_in,
                              void* d_out, int out_size, void* d_ws, size_t ws_size,
                              hipStream_t stream)
{
    const float* q  = (const float*)d_in[0];
    const float* k  = (const float*)d_in[1];
    const float* v  = (const float*)d_in[2];
    const float* Wi = (const float*)d_in[3];
    const float* bi = (const float*)d_in[4];
    const float* Wo = (const float*)d_in[5];
    const float* bo = (const float*)d_in[6];

    float* out      = (float*)d_out;
    float* attn_out = out;                 // [1024,4,256]
    float* cmask    = out + 1048576;       // [1024,1024]

    _Float16* Ppack    = (_Float16*)d_ws;
    float*    attn_pre = (float*)((char*)d_ws + 18874368);
    _Float16* pmask    = (_Float16*)((char*)d_ws + 23068672);
    _Float16* X16      = (_Float16*)((char*)d_ws + 90177536);
    _Float16* W16      = (_Float16*)((char*)d_ws + 96468992);

    cvt_kernel<<<1824, 256, 0, stream>>>(q, k, v, Wi, X16, W16);
    proj_kernel<<<1152, 256, 0, stream>>>(X16, W16, bi, Ppack);
    attn_kernel<<<2048, 512, 0, stream>>>(Ppack, attn_pre, pmask);
    tail_kernel<<<768, 256, 0, stream>>>(pmask, cmask, attn_pre, Wo, bo, attn_out);
}